// Round 4
// baseline (4421.253 us; speedup 1.0000x reference)
//
#include <hip/hip_runtime.h>

#define N_NODES 100000
#define N_EDGES 1600000
#define N_GRAPHS 128
#define IN_CH 768
#define OUT_CH 128
#define NB 782          // ceil(N_NODES/128) buckets of 128 nodes
#define E2 (2 * N_EDGES)

using short8 = __attribute__((ext_vector_type(8))) short;
using f32x4  = __attribute__((ext_vector_type(4))) float;

__device__ __forceinline__ float bf2f(unsigned short u) {
    return __uint_as_float(((unsigned)u) << 16);
}
__device__ __forceinline__ unsigned short f2bf(float f) {
    unsigned u = __float_as_uint(f);
    u += 0x7fffu + ((u >> 16) & 1u);   // round-to-nearest-even
    return (unsigned short)(u >> 16);
}
__device__ __forceinline__ float load_f(const void* p, size_t i, int f32) {
    return f32 ? ((const float*)p)[i] : bf2f(((const unsigned short*)p)[i]);
}
__device__ __forceinline__ float lo16(unsigned p) { return __uint_as_float((p & 0xffffu) << 16); }
__device__ __forceinline__ float hi16(unsigned p) { return __uint_as_float(p & 0xffff0000u); }

// ---------------------------------------------------------------- dtype detect
__global__ void k_detect(const unsigned short* __restrict__ x, int* flag) {
    __shared__ int s;
    if (threadIdx.x == 0) s = 0;
    __syncthreads();
    int bad = 0;
    for (int j = threadIdx.x; j < 8192; j += 256) {
        float v = bf2f(x[j]);
        if (!(v > -64.f && v < 64.f)) bad = 1;
    }
    if (bad) atomicOr(&s, 1);
    __syncthreads();
    if (threadIdx.x == 0) *flag = s;
}

// ---------------------------------------------------------------- init + weight canonicalization
__global__ void k_init(const int* __restrict__ flag, int* deg, unsigned* pooled, int* root,
                       const void* Wc, const void* bc, const void* W0, const void* b0,
                       const void* W1, const void* b1, const void* W2, const void* b2,
                       unsigned short* Wt, float* fbc, float* fW0, float* fb0,
                       float* fW1, float* fb1, float* fW2, float* fb2) {
    int f32 = *flag;
    int i = blockIdx.x * blockDim.x + threadIdx.x;
    if (i < N_NODES) deg[i] = 0;
    if (i < N_GRAPHS * OUT_CH) pooled[i] = 0u;
    if (i < N_GRAPHS) root[i] = 0;
    if (i < IN_CH * OUT_CH) {
        int n = i / IN_CH, k = i - n * IN_CH;     // Wt[n][k] = W_conv[k][n], bf16
        Wt[i] = f32 ? f2bf(((const float*)Wc)[k * OUT_CH + n])
                    : ((const unsigned short*)Wc)[k * OUT_CH + n];
        fW0[i] = load_f(W0, i, f32);
    }
    if (i < 2 * OUT_CH * OUT_CH) fW1[i] = load_f(W1, i, f32);
    if (i < OUT_CH * 2) fW2[i] = load_f(W2, i, f32);
    if (i < OUT_CH) { fbc[i] = load_f(bc, i, f32); fb0[i] = load_f(b0, i, f32); fb1[i] = load_f(b1, i, f32); }
    if (i < 2) fb2[i] = load_f(b2, i, f32);
}

// ---------------------------------------------------------------- degree count
__global__ void k_count(const int* __restrict__ src, const int* __restrict__ dst, int* deg) {
    int i = blockIdx.x * blockDim.x + threadIdx.x;
    if (i >= N_EDGES) return;
    atomicAdd(&deg[src[i]], 1);
    atomicAdd(&deg[dst[i]], 1);
}

__global__ void k_dinv(const int* __restrict__ deg, float* dinv) {
    int i = blockIdx.x * blockDim.x + threadIdx.x;
    if (i >= N_NODES) return;
    int d = deg[i]; if (d < 0) d = 0;
    dinv[i] = rsqrtf((float)(d + 1));           // +1 self-loop
}

// ---------------------------------------------------------------- bucket sums from deg
__global__ void k_bsum(const int* __restrict__ deg, int* bsum) {
    int b = blockIdx.x, t = threadIdx.x;       // 128 threads
    int idx = b * 128 + t;
    int v = (idx < N_NODES) ? deg[idx] : 0;
#pragma unroll
    for (int off = 32; off > 0; off >>= 1) v += __shfl_down(v, off);
    __shared__ int ws[2];
    if ((t & 63) == 0) ws[t >> 6] = v;
    __syncthreads();
    if (t == 0) bsum[b] = ws[0] + ws[1];
}

// ---------------------------------------------------------------- bucket exclusive scan (1 block)
__global__ void k_bscan(const int* __restrict__ bsum, int* base, int* cursor) {
    __shared__ int s[256];
    int tid = threadIdx.x;
    int v[4]; int t = 0;
#pragma unroll
    for (int j = 0; j < 4; j++) {
        int idx = tid * 4 + j;
        v[j] = (idx < NB) ? bsum[idx] : 0;
        t += v[j];
    }
    s[tid] = t;
    __syncthreads();
    for (int off = 1; off < 256; off <<= 1) {
        int add = (tid >= off) ? s[tid - off] : 0;
        __syncthreads();
        s[tid] += add;
        __syncthreads();
    }
    int excl = s[tid] - t;
#pragma unroll
    for (int j = 0; j < 4; j++) {
        int idx = tid * 4 + j;
        if (idx < NB) { base[idx] = excl; cursor[idx] = excl; }
        excl += v[j];
    }
    if (tid == 255) base[NB] = s[255];
}

// ---------------------------------------------------------------- bucket scatter (4B packed records)
__global__ void k_scatter(const int* __restrict__ src, const int* __restrict__ dst,
                          int* cursor, unsigned* part) {
    int i = blockIdx.x * blockDim.x + threadIdx.x;
    if (i >= N_EDGES) return;
    int s = src[i], d = dst[i];
    int p1 = atomicAdd(&cursor[d >> 7], 1);
    part[p1] = ((unsigned)s << 7) | (unsigned)(d & 127);    // edge s->d in bucket(d)
    int p2 = atomicAdd(&cursor[s >> 7], 1);
    part[p2] = ((unsigned)d << 7) | (unsigned)(s & 127);    // edge d->s in bucket(s)
}

// ---------------------------------------------------------------- GEMM h = x @ W_conv (bf16 MFMA, 128x128 tile)
#define MBLK 128
#define BK 64
#define LSTR 72   // padded LDS row stride in shorts (144 B, 16-aligned)

__global__ __launch_bounds__(256) void k_gemm(const int* __restrict__ flag,
                                              const void* __restrict__ xv,
                                              const unsigned short* __restrict__ Wt,
                                              unsigned short* __restrict__ h) {
    __shared__ __align__(16) unsigned short As[MBLK * LSTR];
    __shared__ __align__(16) unsigned short Bs[OUT_CH * LSTR];
    const int f32 = *flag;
    const int tid = threadIdx.x;
    const int wave = tid >> 6, lane = tid & 63;
    const int quad = lane >> 4, l16 = lane & 15;
    const int wm = (wave >> 1) * 64, wn = (wave & 1) * 64;
    const int row0 = blockIdx.x * MBLK;

    f32x4 acc[4][4];
#pragma unroll
    for (int mt = 0; mt < 4; mt++)
#pragma unroll
        for (int nt = 0; nt < 4; nt++) acc[mt][nt] = (f32x4){0.f, 0.f, 0.f, 0.f};

    for (int k0 = 0; k0 < IN_CH; k0 += BK) {
#pragma unroll
        for (int i = 0; i < 4; i++) {
            int chunk = tid + i * 256;
            int r = chunk >> 3, c8 = (chunk & 7) << 3;
            int gr = row0 + r; if (gr >= N_NODES) gr = N_NODES - 1;
            uint4 va;
            if (f32) {
                const float* xp = (const float*)xv + (size_t)gr * IN_CH + k0 + c8;
                unsigned short t[8];
#pragma unroll
                for (int j = 0; j < 8; j++) t[j] = f2bf(xp[j]);
                va = *(const uint4*)t;
            } else {
                va = *(const uint4*)((const unsigned short*)xv + (size_t)gr * IN_CH + k0 + c8);
            }
            *(uint4*)&As[r * LSTR + c8] = va;
            uint4 vb = *(const uint4*)(Wt + (size_t)r * IN_CH + k0 + c8);
            *(uint4*)&Bs[r * LSTR + c8] = vb;
        }
        __syncthreads();
#pragma unroll
        for (int kk = 0; kk < BK; kk += 32) {
            short8 af[4], bf[4];
#pragma unroll
            for (int mt = 0; mt < 4; mt++)
                af[mt] = *(const short8*)&As[(wm + mt * 16 + l16) * LSTR + kk + quad * 8];
#pragma unroll
            for (int nt = 0; nt < 4; nt++)
                bf[nt] = *(const short8*)&Bs[(wn + nt * 16 + l16) * LSTR + kk + quad * 8];
#pragma unroll
            for (int mt = 0; mt < 4; mt++)
#pragma unroll
                for (int nt = 0; nt < 4; nt++)
                    acc[mt][nt] = __builtin_amdgcn_mfma_f32_16x16x32_bf16(af[mt], bf[nt], acc[mt][nt], 0, 0, 0);
        }
        __syncthreads();
    }

#pragma unroll
    for (int mt = 0; mt < 4; mt++) {
#pragma unroll
        for (int nt = 0; nt < 4; nt++) {
            int col = wn + nt * 16 + l16;
#pragma unroll
            for (int r = 0; r < 4; r++) {
                int m = row0 + wm + mt * 16 + quad * 4 + r;
                if (m < N_NODES) h[(size_t)m * OUT_CH + col] = f2bf(acc[mt][nt][r]);
            }
        }
    }
}

// ---------------------------------------------------------------- bucket aggregate + bias + relu + max-pool
// LDS acc layout is channel-permuted: pos j holds global channel (j<64 ? 2j : 2(j-64)+1),
// so lane i's dword gather (ch 2i,2i+1) lands at pos i and 64+i -> stride-1 banks, conflict-free.
__global__ __launch_bounds__(256) void k_bagg(const unsigned short* __restrict__ h,
                                              const unsigned* __restrict__ part,
                                              const int* __restrict__ base,
                                              const float* __restrict__ dinv,
                                              const int* __restrict__ batch,
                                              const float* __restrict__ fbc,
                                              unsigned* pooled) {
    __shared__ float acc[128 * 128];
    __shared__ float dvloc[128];
    __shared__ int bloc[128];
    __shared__ unsigned gmax[4 * 128];
    const int b = blockIdx.x;
    const int nodeBase = b * 128;
    const int nB = (N_NODES - nodeBase < 128) ? (N_NODES - nodeBase) : 128;
    const int tid = threadIdx.x, wave = tid >> 6, lane = tid & 63;

    if (tid < 128) {
        int valid = tid < nB;
        dvloc[tid] = valid ? dinv[nodeBase + tid] : 0.f;
        bloc[tid]  = valid ? batch[nodeBase + tid] : batch[N_NODES - 1];
    }
    gmax[tid] = 0u; gmax[256 + tid] = 0u;
    __syncthreads();

    // self-loop init: acc[n][j] = h[node][c]*dinv^2 (permuted c)
    {
        int j = tid & 127;
        int c = (j < 64) ? (2 * j) : (2 * (j - 64) + 1);
        for (int n = tid >> 7; n < 128; n += 2) {
            float v = 0.f;
            if (n < nB) {
                float dv = dvloc[n];
                v = bf2f(h[(size_t)(nodeBase + n) * OUT_CH + c]) * dv * dv;
            }
            acc[n * 128 + j] = v;
        }
    }
    __syncthreads();

    const int e0 = base[b], e1 = base[b + 1];
    for (int base0 = e0 + wave * 64; base0 < e1; base0 += 256) {
        int idx = base0 + lane;
        unsigned rv = 0u; float wv = 0.f;
        if (idx < e1) {
            rv = part[idx];
            wv = dinv[rv >> 7] * dvloc[rv & 127];
        }
#pragma unroll
        for (int j0 = 0; j0 < 64; j0 += 8) {
            unsigned r8[8], pv8[8]; float w8[8];
#pragma unroll
            for (int k = 0; k < 8; k++) {
                r8[k] = (unsigned)__shfl((int)rv, j0 + k);
                w8[k] = __shfl(wv, j0 + k);
                pv8[k] = *(const unsigned*)(h + (size_t)(r8[k] >> 7) * OUT_CH + lane * 2);
            }
#pragma unroll
            for (int k = 0; k < 8; k++) {
                int dl = (int)(r8[k] & 127u);
                atomicAdd(&acc[dl * 128 + lane],      lo16(pv8[k]) * w8[k]);
                atomicAdd(&acc[dl * 128 + 64 + lane], hi16(pv8[k]) * w8[k]);
            }
        }
    }
    __syncthreads();

    // epilogue: bias + relu + per-graph max
    int j = tid & 127;
    int c = (j < 64) ? (2 * j) : (2 * (j - 64) + 1);
    float bias = fbc[c];
    int g0 = bloc[0];
    int span = bloc[nB - 1] - g0;
    if (span <= 3) {
        for (int n = tid >> 7; n < nB; n += 2) {
            float v = fmaxf(acc[n * 128 + j] + bias, 0.f);
            int gi = bloc[n] - g0;
            atomicMax(&gmax[gi * 128 + j], __float_as_uint(v));
        }
        __syncthreads();
        for (int e = tid; e < (span + 1) * 128; e += 256) {
            int gi = e >> 7, jj = e & 127;
            int cc = (jj < 64) ? (2 * jj) : (2 * (jj - 64) + 1);
            unsigned v = gmax[e];
            if (v) atomicMax(&pooled[(size_t)(g0 + gi) * OUT_CH + cc], v);
        }
    } else {
        for (int n = tid >> 7; n < nB; n += 2) {
            float v = fmaxf(acc[n * 128 + j] + bias, 0.f);
            atomicMax(&pooled[(size_t)bloc[n] * OUT_CH + c], __float_as_uint(v));
        }
    }
}

// ---------------------------------------------------------------- root (first node per graph)
__global__ void k_root(const int* __restrict__ batch, int* root) {
    int i = blockIdx.x * blockDim.x + threadIdx.x;
    if (i >= N_NODES) return;
    int b = batch[i];
    if (i == 0 || batch[i - 1] != b) root[b] = i;
}

// ---------------------------------------------------------------- news = relu(x[root] @ W0 + b0)
__global__ __launch_bounds__(128) void k_news(const int* __restrict__ flag,
                                              const void* __restrict__ x,
                                              const int* __restrict__ root,
                                              const float* __restrict__ W0,
                                              const float* __restrict__ b0,
                                              float* news) {
    __shared__ float xs[IN_CH];
    int f32 = *flag;
    int g = blockIdx.x, c = threadIdx.x;
    int r = root[g];
    for (int j = c; j < IN_CH; j += 128) xs[j] = load_f(x, (size_t)r * IN_CH + j, f32);
    __syncthreads();
    float acc = 0.f;
#pragma unroll 8
    for (int k = 0; k < IN_CH; k++) acc += xs[k] * W0[k * OUT_CH + c];
    news[g * OUT_CH + c] = fmaxf(acc + b0[c], 0.f);
}

// ---------------------------------------------------------------- head: lin1 + lin2 + log_softmax
__global__ __launch_bounds__(128) void k_final(const int* __restrict__ flag,
                                               const float* __restrict__ news,
                                               const unsigned* __restrict__ pooled,
                                               const float* __restrict__ W1,
                                               const float* __restrict__ b1,
                                               const float* __restrict__ W2,
                                               const float* __restrict__ b2,
                                               void* out) {
    __shared__ float ins[2 * OUT_CH];
    __shared__ float h2s[OUT_CH];
    int g = blockIdx.x, c = threadIdx.x;
    ins[c] = news[g * OUT_CH + c];
    ins[OUT_CH + c] = __uint_as_float(pooled[g * OUT_CH + c]);
    __syncthreads();
    float acc = 0.f;
#pragma unroll 8
    for (int k = 0; k < 2 * OUT_CH; k++) acc += ins[k] * W1[k * OUT_CH + c];
    h2s[c] = fmaxf(acc + b1[c], 0.f);
    __syncthreads();
    if (c == 0) {
        float l0 = b2[0], l1 = b2[1];
        for (int k = 0; k < OUT_CH; k++) { float v = h2s[k]; l0 += v * W2[k * 2]; l1 += v * W2[k * 2 + 1]; }
        float m = fmaxf(l0, l1);
        float ls = m + logf(expf(l0 - m) + expf(l1 - m));
        if (*flag) {
            ((float*)out)[g * 2]     = l0 - ls;
            ((float*)out)[g * 2 + 1] = l1 - ls;
        } else {
            ((unsigned short*)out)[g * 2]     = f2bf(l0 - ls);
            ((unsigned short*)out)[g * 2 + 1] = f2bf(l1 - ls);
        }
    }
}

// ---------------------------------------------------------------- launch
extern "C" void kernel_launch(void* const* d_in, const int* in_sizes, int n_in,
                              void* d_out, int out_size, void* d_ws, size_t ws_size,
                              hipStream_t stream) {
    const void* x     = d_in[0];
    const int*  ei    = (const int*)d_in[1];
    const int*  batch = (const int*)d_in[2];
    const void* Wc    = d_in[4];
    const void* bc    = d_in[5];
    const void* W0    = d_in[6];
    const void* b0    = d_in[7];
    const void* W1    = d_in[8];
    const void* b1    = d_in[9];
    const void* W2    = d_in[10];
    const void* b2    = d_in[11];
    const int* src = ei;
    const int* dst = ei + N_EDGES;

    char* p = (char*)d_ws;
    auto carve = [&](size_t bytes) -> void* {
        void* r = (void*)p;
        p += (bytes + 255) & ~(size_t)255;
        return r;
    };
    int*      flag      = (int*)carve(4);
    int*      deg       = (int*)carve((size_t)N_NODES * 4);
    float*    dinv      = (float*)carve((size_t)N_NODES * 4);
    int*      bsum      = (int*)carve((size_t)NB * 4);
    int*      bbase     = (int*)carve((size_t)(NB + 1) * 4);
    int*      bcursor   = (int*)carve((size_t)NB * 4);
    int*      root      = (int*)carve(128 * 4);
    unsigned* pooled    = (unsigned*)carve((size_t)N_GRAPHS * OUT_CH * 4);
    float*    news      = (float*)carve((size_t)N_GRAPHS * OUT_CH * 4);
    unsigned short* Wt  = (unsigned short*)carve((size_t)IN_CH * OUT_CH * 2);
    float*    fW0       = (float*)carve((size_t)IN_CH * OUT_CH * 4);
    float*    fW1       = (float*)carve((size_t)2 * OUT_CH * OUT_CH * 4);
    float*    fW2       = (float*)carve((size_t)OUT_CH * 2 * 4);
    float*    fbc       = (float*)carve((size_t)OUT_CH * 4);
    float*    fb0       = (float*)carve((size_t)OUT_CH * 4);
    float*    fb1       = (float*)carve((size_t)OUT_CH * 4);
    float*    fb2       = (float*)carve(2 * 4);
    unsigned* part      = (unsigned*)carve((size_t)E2 * 4);
    unsigned short* h   = (unsigned short*)carve((size_t)N_NODES * OUT_CH * 2);

    k_detect <<<1, 256, 0, stream>>>((const unsigned short*)x, flag);
    k_init   <<<391, 256, 0, stream>>>(flag, deg, pooled, root, Wc, bc, W0, b0, W1, b1, W2, b2,
                                       Wt, fbc, fW0, fb0, fW1, fb1, fW2, fb2);
    k_count  <<<6250, 256, 0, stream>>>(src, dst, deg);
    k_dinv   <<<391, 256, 0, stream>>>(deg, dinv);
    k_bsum   <<<NB, 128, 0, stream>>>(deg, bsum);
    k_bscan  <<<1, 256, 0, stream>>>(bsum, bbase, bcursor);
    k_scatter<<<6250, 256, 0, stream>>>(src, dst, bcursor, part);
    k_gemm   <<<(N_NODES + MBLK - 1) / MBLK, 256, 0, stream>>>(flag, x, Wt, h);
    k_bagg   <<<NB, 256, 0, stream>>>(h, part, bbase, dinv, batch, fbc, pooled);
    k_root   <<<391, 256, 0, stream>>>(batch, root);
    k_news   <<<N_GRAPHS, 128, 0, stream>>>(flag, x, root, fW0, fb0, news);
    k_final  <<<N_GRAPHS, 128, 0, stream>>>(flag, news, pooled, fW1, fb1, fW2, fb2, d_out);
}